// Round 4
// baseline (868.029 us; speedup 1.0000x reference)
//
#include <hip/hip_runtime.h>
#include <hip/hip_bf16.h>

#define BB 32
#define LL 128
#define DD 400
#define KK 40
#define EE 416   // e padded to 13*32
#define SDN 50   // d-slot count (400/8)
#define SEN 52   // e-slot count (416/8)

typedef __attribute__((ext_vector_type(8)))  short  bfrag;   // 8 bf16 = 4 VGPRs
typedef __attribute__((ext_vector_type(16))) float  ffrag;   // 16 fp32 acc

static __device__ __forceinline__ short f2bf(float f) {
    union { float f; unsigned u; } v; v.f = f;
    unsigned r = (v.u + 0x7FFF + ((v.u >> 16) & 1)) >> 16;
    return (short)r;
}

// ---------------------------------------------------------------------------
// Fused prep kernel: block-range dispatch.
//  [0, 1632)      : Hslots / Cslots bf16 re-layout
//  [1632, 4882)   : Uslots bf16 re-layout (Ut: [k][sd][e][8])
//  [4882, 6162)   : SD/SE fp32 dot products
// ---------------------------------------------------------------------------
__global__ __launch_bounds__(256) void k_prep(
    const float* __restrict__ H, const float* __restrict__ C,
    const float* __restrict__ U,
    const float* __restrict__ Wd, const float* __restrict__ We,
    short* __restrict__ Hs, short* __restrict__ Cs, short* __restrict__ Us,
    float* __restrict__ SD, float* __restrict__ SE)
{
    const int bid = blockIdx.x;
    const int t = threadIdx.x;
    __shared__ float wsh[2*DD];

    if (bid < 1632) {                    // ---- H/C slots ----
        int id = bid * 256 + t;
        if (id < BB*SDN*LL) {
            int b = id / (SDN*LL); int r = id % (SDN*LL);
            int sd = r / LL; int h = r % LL;
            const float* src = H + ((size_t)(b*LL + h))*DD + sd*8;
            bfrag v;
#pragma unroll
            for (int j = 0; j < 8; ++j) v[j] = f2bf(src[j]);
            *(bfrag*)(Hs + (size_t)id*8) = v;
        } else {
            id -= BB*SDN*LL;
            int b = id / (SEN*LL); int r = id % (SEN*LL);
            int se = r / LL; int c = r % LL;
            bfrag v;
#pragma unroll
            for (int j = 0; j < 8; ++j) {
                int e = se*8 + j;
                v[j] = (e < DD) ? f2bf(C[((size_t)(b*LL + c))*DD + e]) : (short)0;
            }
            *(bfrag*)(Cs + (size_t)id*8) = v;
        }
    } else if (bid < 4882) {             // ---- U slots ----
        int id = (bid - 1632) * 256 + t;     // < 40*50*416
        int k = id / (SDN*EE); int r = id % (SDN*EE);
        int sd = r / EE; int e = r % EE;
        bfrag v;
#pragma unroll
        for (int j = 0; j < 8; ++j)
            v[j] = (e < DD) ? f2bf(U[((size_t)k*DD + sd*8 + j)*DD + e]) : (short)0;
        *(bfrag*)(Us + (size_t)id*8) = v;
    } else {                             // ---- SD / SE ----
        int sb = bid - 4882;
        const int k = sb % KK;
        const int b = sb / KK;
        float* wd = wsh; float* we = wsh + DD;
        for (int f = t; f < DD; f += 256) { wd[f] = Wd[k*DD + f]; we[f] = We[k*DD + f]; }
        __syncthreads();
        const int row = t & 127;
        const float* src = (t < 128) ? (H + (size_t)(b*LL + row)*DD)
                                     : (C + (size_t)(b*LL + row)*DD);
        const float* w = (t < 128) ? wd : we;
        float s = 0.f;
        for (int d = 0; d < DD; d += 4) {
            float4 v = *(const float4*)(src + d);
            s = fmaf(v.x, w[d+0], s); s = fmaf(v.y, w[d+1], s);
            s = fmaf(v.z, w[d+2], s); s = fmaf(v.w, w[d+3], s);
        }
        if (t < 128) SD[(b*KK + k)*LL + row] = s;
        else         SE[(b*KK + k)*LL + row] = s;
    }
}

// ---------------------------------------------------------------------------
// Main MFMA kernel, round 4: mt-pass split (halved Tacc) + double-buffered
// register prefetch in both phases; __launch_bounds__(256,3) for 3 waves/SIMD.
// ---------------------------------------------------------------------------
__global__ __launch_bounds__(256, 3) void k_mfma(
    const short* __restrict__ Hs, const short* __restrict__ Cs,
    const short* __restrict__ Us,
    const float* __restrict__ SD, const float* __restrict__ SE,
    const float* __restrict__ bvec, const float* __restrict__ mask,
    const int* __restrict__ heads, const int* __restrict__ tags,
    float* __restrict__ A8, float* __restrict__ tgt)
{
    const int k = blockIdx.x;
    const int b = blockIdx.y;
    const int t = threadIdx.x;
    const int w  = t >> 6;
    const int l  = t & 63;
    const int l31 = l & 31;
    const int kh  = l >> 5;        // 0/1
    const int wm  = w >> 1;        // phase1: e-half; phase2: h-half
    const int wn  = w & 1;         // phase1: h-half; phase2: c-half

    __shared__ short Tbuf[16*LL*8];   // [s_e(16)][h(128)][8]  32 KB

    const bfrag* UsF = (const bfrag*)Us;
    const bfrag* HsF = (const bfrag*)Hs;
    const bfrag* CsF = (const bfrag*)Cs;

    ffrag Sacc[2][2];
#pragma unroll
    for (int a = 0; a < 2; ++a)
#pragma unroll
        for (int c2 = 0; c2 < 2; ++c2)
#pragma unroll
            for (int r = 0; r < 16; ++r) Sacc[a][c2][r] = 0.f;

    const int usK = k * (SDN * EE);
    const int hsB = b * (SDN * LL);
    const int csB = b * (SEN * LL);

    for (int chunk = 0; chunk < 4; ++chunk) {
        const int e0  = chunk * 128;
        const int NEc = (chunk < 3) ? 128 : 32;
        const int nmt = (NEc == 128) ? 2 : ((wm == 0) ? 1 : 0);

        // ---- Phase 1: two mt passes, Tacc = 32 regs, prefetch depth 1 ----
        for (int mt = 0; mt < nmt; ++mt) {
            ffrag T0, T1;
#pragma unroll
            for (int r = 0; r < 16; ++r) { T0[r] = 0.f; T1[r] = 0.f; }
            const int eg = e0 + 64*wm + 32*mt + l31;
            const int hg = 64*wn + l31;
            bfrag aC  = UsF[usK + kh*EE + eg];
            bfrag b0C = HsF[hsB + kh*LL + hg];
            bfrag b1C = HsF[hsB + kh*LL + hg + 32];
            for (int ds = 0; ds < 25; ++ds) {
                bfrag aN = aC, b0N = b0C, b1N = b1C;
                if (ds < 24) {
                    const int sdl = 2*ds + 2 + kh;
                    aN  = UsF[usK + sdl*EE + eg];
                    b0N = HsF[hsB + sdl*LL + hg];
                    b1N = HsF[hsB + sdl*LL + hg + 32];
                }
                T0 = __builtin_amdgcn_mfma_f32_32x32x16_bf16(aC, b0C, T0, 0, 0, 0);
                T1 = __builtin_amdgcn_mfma_f32_32x32x16_bf16(aC, b1C, T1, 0, 0, 0);
                aC = aN; b0C = b0N; b1C = b1N;
            }
            // write T tiles to LDS in phase-2 A-fragment layout
#pragma unroll
            for (int nt = 0; nt < 2; ++nt) {
                const int h = 64*wn + 32*nt + l31;
#pragma unroll
                for (int r = 0; r < 16; r += 2) {
                    int e_loc = 64*wm + 32*mt + (r&3) + 8*(r>>2) + 4*kh;
                    int s_e = e_loc >> 3, e7 = e_loc & 7;
                    float v0 = nt ? T1[r]   : T0[r];
                    float v1 = nt ? T1[r+1] : T0[r+1];
                    unsigned lo = (unsigned short)f2bf(v0);
                    unsigned hi = (unsigned short)f2bf(v1);
                    *(unsigned*)(&Tbuf[((size_t)s_e*LL + h)*8 + e7]) = lo | (hi << 16);
                }
            }
        }
        __syncthreads();

        // ---- Phase 2: prefetch C frags ----
        const int esteps = NEc >> 4;
        const int cg0 = 64*wn + l31;
        const int hgA = 64*wm + l31;
        const int segBase = e0 >> 3;
        bfrag c0C = CsF[csB + (segBase + kh)*LL + cg0];
        bfrag c1C = CsF[csB + (segBase + kh)*LL + cg0 + 32];
        for (int es = 0; es < esteps; ++es) {
            const int sel = 2*es + kh;
            bfrag c0N = c0C, c1N = c1C;
            if (es + 1 < esteps) {
                c0N = CsF[csB + (segBase + sel + 2)*LL + cg0];
                c1N = CsF[csB + (segBase + sel + 2)*LL + cg0 + 32];
            }
            bfrag a0 = *(const bfrag*)(&Tbuf[((size_t)sel*LL + hgA)*8]);
            bfrag a1 = *(const bfrag*)(&Tbuf[((size_t)sel*LL + hgA + 32)*8]);
            Sacc[0][0] = __builtin_amdgcn_mfma_f32_32x32x16_bf16(a0, c0C, Sacc[0][0], 0, 0, 0);
            Sacc[0][1] = __builtin_amdgcn_mfma_f32_32x32x16_bf16(a0, c1C, Sacc[0][1], 0, 0, 0);
            Sacc[1][0] = __builtin_amdgcn_mfma_f32_32x32x16_bf16(a1, c0C, Sacc[1][0], 0, 0, 0);
            Sacc[1][1] = __builtin_amdgcn_mfma_f32_32x32x16_bf16(a1, c1C, Sacc[1][1], 0, 0, 0);
            c0C = c0N; c1C = c1N;
        }
        __syncthreads();   // Tbuf reused next chunk
    }

    // ---- Epilogue ----
    const float bk = bvec[k];
    const float* SDb = SD + ((size_t)b*KK + k)*LL;
    const float* SEb = SE + ((size_t)b*KK + k)*LL;
    float* Ab = A8 + ((size_t)((k & 7)*BB + b))*LL*LL;

#pragma unroll
    for (int at = 0; at < 2; ++at) {
#pragma unroll
        for (int bt = 0; bt < 2; ++bt) {
            const int c = 64*wn + 32*bt + l31;
            const float mc = mask[b*LL + c];
            const float sev = SEb[c];
            const int headc = heads[b*LL + c];
            const int tagc  = tags[b*LL + c];
#pragma unroll
            for (int r = 0; r < 16; ++r) {
                int h = 64*wm + 32*at + (r&3) + 8*(r>>2) + 4*kh;
                if (h == c) continue;
                float mh = mask[b*LL + h];
                if (mh == 0.f || mc == 0.f) continue;
                float eng = Sacc[at][bt][r] + SDb[h] + sev + bk;
                atomicAdd(&Ab[h*LL + c], __expf(eng));
                if (c >= 1 && tagc == k && headc == h) atomicAdd(&tgt[b], eng);
            }
        }
    }
}

// ---------------------------------------------------------------------------
// Sum the 8 A-slices into As (parallel; removes this from k_logdet)
// ---------------------------------------------------------------------------
__global__ __launch_bounds__(256) void k_asum(
    const float4* __restrict__ A8, float4* __restrict__ As)
{
    const int f4 = blockIdx.x * 256 + threadIdx.x;   // < 32*4096
    const int b = f4 >> 12, r = f4 & 4095;
    float4 s = make_float4(0.f, 0.f, 0.f, 0.f);
#pragma unroll
    for (int g = 0; g < 8; ++g) {
        float4 v = A8[((size_t)(g*BB + b))*4096 + r];
        s.x += v.x; s.y += v.y; s.z += v.z; s.w += v.w;
    }
    As[f4] = s;
}

// ---------------------------------------------------------------------------
// Register-resident LU logdet (one block/batch, 16x16 thread grid, 8x8 regs).
// ---------------------------------------------------------------------------
__global__ __launch_bounds__(256) void k_logdet(
    const float* __restrict__ Asg, const int* __restrict__ lengths,
    const float* __restrict__ tgt, float* __restrict__ out)
{
    const int b = blockIdx.x;
    const int t = threadIdx.x;
    const int rg = t >> 4;      // 0..15 row-group
    const int cg = t & 15;      // 0..15 col-group

    __shared__ float As[LL*LL];     // 64 KB
    __shared__ float Dg[128];       // col sums, then pivot stash
    __shared__ float Lbuf[128];
    __shared__ float Ubuf[128];
    __shared__ float red[256];

    const float4* As4 = (const float4*)Asg;
    for (int f4 = t; f4 < 4096; f4 += 256)
        ((float4*)As)[f4] = As4[(size_t)b*4096 + f4];
    __syncthreads();

    if (t < 128) {
        float s = 0.f;
        for (int hr = 0; hr < LL; ++hr) s += As[hr*LL + t];
        Dg[t] = s * (1.0f + 1e-4f) + 1e-6f;
    }
    __syncthreads();

    const int n1 = lengths[b] - 1;
    float m[8][8];
#pragma unroll
    for (int r = 0; r < 8; ++r) {
        const int i = 8*rg + r;
#pragma unroll
        for (int c = 0; c < 8; ++c) {
            const int j = 8*cg + c;
            float v;
            if (i < n1 && j < n1)
                v = ((i == j) ? Dg[i+1] : 0.f) - As[(i+1)*LL + (j+1)];
            else
                v = (i == j) ? 1.f : 0.f;
            m[r][c] = v;
        }
    }
    __syncthreads();   // done reading Dg/As; Dg reused as pivot stash

    for (int j = 0; j < 127; ++j) {
        const int jg = j >> 3, jl = j & 7;
        if (cg == jg) {
#pragma unroll
            for (int c = 0; c < 8; ++c) {
                if (c == jl) {
#pragma unroll
                    for (int r = 0; r < 8; ++r) Lbuf[8*rg + r] = m[r][c];
                }
            }
        }
        if (rg == jg) {
#pragma unroll
            for (int r = 0; r < 8; ++r) {
                if (r == jl) {
#pragma unroll
                    for (int c = 0; c < 8; ++c) Ubuf[8*cg + c] = m[r][c];
                }
            }
        }
        __syncthreads();

        const float piv = Lbuf[j];
        if (t == j) Dg[j] = piv;
        const float rp = 1.0f / piv;
        float lr[8], ur[8];
#pragma unroll
        for (int r = 0; r < 8; ++r) lr[r] = Lbuf[8*rg + r] * rp;
#pragma unroll
        for (int c = 0; c < 8; ++c) ur[c] = Ubuf[8*cg + c];
#pragma unroll
        for (int r = 0; r < 8; ++r)
#pragma unroll
            for (int c = 0; c < 8; ++c)
                m[r][c] = fmaf(-lr[r], ur[c], m[r][c]);
        __syncthreads();
    }

    float lsum = 0.f;
    if (t < 127) lsum = logf(Dg[t]);
    red[t] = lsum;
    __syncthreads();
    for (int off = 128; off >= 1; off >>= 1) {
        if (t < off) red[t] += red[t + off];
        __syncthreads();
    }
    if (t == 0) out[b] = red[0] - tgt[b];
}

// ---------------------------------------------------------------------------
extern "C" void kernel_launch(void* const* d_in, const int* in_sizes, int n_in,
                              void* d_out, int out_size, void* d_ws, size_t ws_size,
                              hipStream_t stream) {
    const float* H    = (const float*)d_in[0];
    const float* C    = (const float*)d_in[1];
    const float* Wd   = (const float*)d_in[2];
    const float* We   = (const float*)d_in[3];
    const float* U    = (const float*)d_in[4];
    const float* bv   = (const float*)d_in[5];
    const float* mask = (const float*)d_in[6];
    const int* heads  = (const int*)d_in[7];
    const int* tags   = (const int*)d_in[8];
    const int* lens   = (const int*)d_in[9];
    float* out = (float*)d_out;

    // workspace layout
    char* p = (char*)d_ws;
    float* A8  = (float*)p;                 p += (size_t)8*BB*LL*LL*4;      // 16.78 MB
    float* tgt = (float*)p;                 p += 32*4;
    float* As  = (float*)p;                 p += (size_t)BB*LL*LL*4;        // 2.10 MB
    float* SDp = (float*)p;                 p += (size_t)BB*KK*LL*4;
    float* SEp = (float*)p;                 p += (size_t)BB*KK*LL*4;
    short* Hsp = (short*)p;                 p += (size_t)BB*SDN*LL*8*2;
    short* Csp = (short*)p;                 p += (size_t)BB*SEN*LL*8*2;
    short* Usp = (short*)p;                 p += (size_t)KK*SDN*EE*8*2;

    hipMemsetAsync(d_ws, 0, ((size_t)8*BB*LL*LL + 32)*4, stream);

    k_prep<<<dim3(6162), 256, 0, stream>>>(H, C, U, Wd, We, Hsp, Csp, Usp, SDp, SEp);
    k_mfma<<<dim3(KK, BB), 256, 0, stream>>>(Hsp, Csp, Usp, SDp, SEp, bv, mask,
                                             heads, tags, A8, tgt);
    k_asum<<<dim3(512), 256, 0, stream>>>((const float4*)A8, (float4*)As);
    k_logdet<<<dim3(BB), 256, 0, stream>>>(As, lens, tgt, out);
}

// Round 5
// 457.378 us; speedup vs baseline: 1.8978x; 1.8978x over previous
//
#include <hip/hip_runtime.h>
#include <hip/hip_bf16.h>

#define BB 32
#define LL 128
#define DD 400
#define KK 40
#define EE 416   // e padded to 13*32
#define SDN 50   // d-slot count (400/8)
#define SEN 52   // e-slot count (416/8)

typedef __attribute__((ext_vector_type(8)))  short  bfrag;   // 8 bf16 = 4 VGPRs
typedef __attribute__((ext_vector_type(16))) float  ffrag;   // 16 fp32 acc

static __device__ __forceinline__ short f2bf(float f) {
    union { float f; unsigned u; } v; v.f = f;
    unsigned r = (v.u + 0x7FFF + ((v.u >> 16) & 1)) >> 16;
    return (short)r;
}

// ---------------------------------------------------------------------------
// Fused prep kernel: block-range dispatch.
//  [0, 1632)      : Hslots / Cslots bf16 re-layout
//  [1632, 4882)   : Uslots bf16 re-layout (Ut: [k][sd][e][8])
//  [4882, 6162)   : SD/SE fp32 dot products
// ---------------------------------------------------------------------------
__global__ __launch_bounds__(256) void k_prep(
    const float* __restrict__ H, const float* __restrict__ C,
    const float* __restrict__ U,
    const float* __restrict__ Wd, const float* __restrict__ We,
    short* __restrict__ Hs, short* __restrict__ Cs, short* __restrict__ Us,
    float* __restrict__ SD, float* __restrict__ SE)
{
    const int bid = blockIdx.x;
    const int t = threadIdx.x;
    __shared__ float wsh[2*DD];

    if (bid < 1632) {                    // ---- H/C slots ----
        int id = bid * 256 + t;
        if (id < BB*SDN*LL) {
            int b = id / (SDN*LL); int r = id % (SDN*LL);
            int sd = r / LL; int h = r % LL;
            const float* src = H + ((size_t)(b*LL + h))*DD + sd*8;
            bfrag v;
#pragma unroll
            for (int j = 0; j < 8; ++j) v[j] = f2bf(src[j]);
            *(bfrag*)(Hs + (size_t)id*8) = v;
        } else {
            id -= BB*SDN*LL;
            int b = id / (SEN*LL); int r = id % (SEN*LL);
            int se = r / LL; int c = r % LL;
            bfrag v;
#pragma unroll
            for (int j = 0; j < 8; ++j) {
                int e = se*8 + j;
                v[j] = (e < DD) ? f2bf(C[((size_t)(b*LL + c))*DD + e]) : (short)0;
            }
            *(bfrag*)(Cs + (size_t)id*8) = v;
        }
    } else if (bid < 4882) {             // ---- U slots ----
        int id = (bid - 1632) * 256 + t;     // < 40*50*416
        int k = id / (SDN*EE); int r = id % (SDN*EE);
        int sd = r / EE; int e = r % EE;
        bfrag v;
#pragma unroll
        for (int j = 0; j < 8; ++j)
            v[j] = (e < DD) ? f2bf(U[((size_t)k*DD + sd*8 + j)*DD + e]) : (short)0;
        *(bfrag*)(Us + (size_t)id*8) = v;
    } else {                             // ---- SD / SE ----
        int sb = bid - 4882;
        const int k = sb % KK;
        const int b = sb / KK;
        float* wd = wsh; float* we = wsh + DD;
        for (int f = t; f < DD; f += 256) { wd[f] = Wd[k*DD + f]; we[f] = We[k*DD + f]; }
        __syncthreads();
        const int row = t & 127;
        const float* src = (t < 128) ? (H + (size_t)(b*LL + row)*DD)
                                     : (C + (size_t)(b*LL + row)*DD);
        const float* w = (t < 128) ? wd : we;
        float s = 0.f;
        for (int d = 0; d < DD; d += 4) {
            float4 v = *(const float4*)(src + d);
            s = fmaf(v.x, w[d+0], s); s = fmaf(v.y, w[d+1], s);
            s = fmaf(v.z, w[d+2], s); s = fmaf(v.w, w[d+3], s);
        }
        if (t < 128) SD[(b*KK + k)*LL + row] = s;
        else         SE[(b*KK + k)*LL + row] = s;
    }
}

// ---------------------------------------------------------------------------
// Main MFMA kernel = exact round-3 structure (84 VGPR + 128 AGPR, waves=2,
// no spills) + XCD-aware block swizzle: xcd (id&7) owns k in [5*xcd,5*xcd+5)
// so the per-XCD Us working set is 3.3 MB (fits 4 MB L2) and each Us slice
// is reused by the 32 b-blocks resident on that XCD.
// ---------------------------------------------------------------------------
__global__ __launch_bounds__(256, 2) void k_mfma(
    const short* __restrict__ Hs, const short* __restrict__ Cs,
    const short* __restrict__ Us,
    const float* __restrict__ SD, const float* __restrict__ SE,
    const float* __restrict__ bvec, const float* __restrict__ mask,
    const int* __restrict__ heads, const int* __restrict__ tags,
    float* __restrict__ A8, float* __restrict__ tgt)
{
    const int id = blockIdx.x;               // 0..1279
    const int slot = id >> 3;                // 0..159
    const int k = (id & 7) * 5 + (slot >> 5);
    const int b = slot & 31;
    const int t = threadIdx.x;
    const int w  = t >> 6;
    const int l  = t & 63;
    const int l31 = l & 31;
    const int kh  = l >> 5;        // 0/1
    const int wm  = w >> 1;        // phase1: e-half; phase2: h-half
    const int wn  = w & 1;         // phase1: h-half; phase2: c-half

    __shared__ short Tbuf[16*LL*8];   // [s_e(16)][h(128)][8]  32 KB

    ffrag Sacc[2][2];
#pragma unroll
    for (int a = 0; a < 2; ++a)
#pragma unroll
        for (int c2 = 0; c2 < 2; ++c2)
#pragma unroll
            for (int r = 0; r < 16; ++r) Sacc[a][c2][r] = 0.f;

    const size_t usK = (size_t)k * SDN * EE;
    const size_t hsB = (size_t)b * SDN * LL;
    const size_t csB = (size_t)b * SEN * LL;

    for (int chunk = 0; chunk < 4; ++chunk) {
        const int e0  = chunk * 128;
        const int NEc = (chunk < 3) ? 128 : 32;
        const int nmt = (NEc == 128) ? 2 : ((wm == 0) ? 1 : 0);

        // ---- Phase 1 ----
        ffrag Tacc[2][2];
#pragma unroll
        for (int a = 0; a < 2; ++a)
#pragma unroll
            for (int c2 = 0; c2 < 2; ++c2)
#pragma unroll
                for (int r = 0; r < 16; ++r) Tacc[a][c2][r] = 0.f;

        if (nmt > 0) {
            for (int ds = 0; ds < 25; ++ds) {
                const int sdl = 2*ds + kh;
                bfrag afr[2], bfr[2];
#pragma unroll
                for (int mt = 0; mt < 2; ++mt) {
                    if (mt < nmt) {
                        int eg = e0 + 64*wm + 32*mt + l31;
                        afr[mt] = *(const bfrag*)(Us + (usK + (size_t)sdl*EE + eg)*8);
                    }
                }
#pragma unroll
                for (int nt = 0; nt < 2; ++nt) {
                    int h = 64*wn + 32*nt + l31;
                    bfr[nt] = *(const bfrag*)(Hs + (hsB + (size_t)sdl*LL + h)*8);
                }
#pragma unroll
                for (int mt = 0; mt < 2; ++mt) {
                    if (mt < nmt) {
#pragma unroll
                        for (int nt = 0; nt < 2; ++nt)
                            Tacc[mt][nt] = __builtin_amdgcn_mfma_f32_32x32x16_bf16(
                                afr[mt], bfr[nt], Tacc[mt][nt], 0, 0, 0);
                    }
                }
            }
            // write Tt tiles to LDS in phase-2 A-fragment layout
#pragma unroll
            for (int mt = 0; mt < 2; ++mt) {
                if (mt < nmt) {
#pragma unroll
                    for (int nt = 0; nt < 2; ++nt) {
                        int h = 64*wn + 32*nt + l31;
#pragma unroll
                        for (int r = 0; r < 16; r += 2) {
                            int e_loc = 64*wm + 32*mt + (r&3) + 8*(r>>2) + 4*kh;
                            int s_e = e_loc >> 3, e7 = e_loc & 7;
                            unsigned lo = (unsigned short)f2bf(Tacc[mt][nt][r]);
                            unsigned hi = (unsigned short)f2bf(Tacc[mt][nt][r+1]);
                            *(unsigned*)(&Tbuf[((size_t)s_e*LL + h)*8 + e7]) =
                                lo | (hi << 16);
                        }
                    }
                }
            }
        }
        __syncthreads();

        // ---- Phase 2 ----
        const int esteps = NEc >> 4;
        for (int es = 0; es < esteps; ++es) {
            const int sel = 2*es + kh;
            bfrag afr[2], bfr[2];
#pragma unroll
            for (int at = 0; at < 2; ++at) {
                int h = 64*wm + 32*at + l31;
                afr[at] = *(const bfrag*)(&Tbuf[((size_t)sel*LL + h)*8]);
            }
#pragma unroll
            for (int bt = 0; bt < 2; ++bt) {
                int c = 64*wn + 32*bt + l31;
                int seg = (e0 >> 3) + sel;
                bfr[bt] = *(const bfrag*)(Cs + (csB + (size_t)seg*LL + c)*8);
            }
#pragma unroll
            for (int at = 0; at < 2; ++at)
#pragma unroll
                for (int bt = 0; bt < 2; ++bt)
                    Sacc[at][bt] = __builtin_amdgcn_mfma_f32_32x32x16_bf16(
                        afr[at], bfr[bt], Sacc[at][bt], 0, 0, 0);
        }
        __syncthreads();   // Tbuf reused next chunk
    }

    // ---- Epilogue ----
    const float bk = bvec[k];
    const float* SDb = SD + ((size_t)b*KK + k)*LL;
    const float* SEb = SE + ((size_t)b*KK + k)*LL;
    float* Ab = A8 + ((size_t)((k & 7)*BB + b))*LL*LL;

#pragma unroll
    for (int at = 0; at < 2; ++at) {
#pragma unroll
        for (int bt = 0; bt < 2; ++bt) {
            const int c = 64*wn + 32*bt + l31;
            const float mc = mask[b*LL + c];
            const float sev = SEb[c];
            const int headc = heads[b*LL + c];
            const int tagc  = tags[b*LL + c];
#pragma unroll
            for (int r = 0; r < 16; ++r) {
                int h = 64*wm + 32*at + (r&3) + 8*(r>>2) + 4*kh;
                if (h == c) continue;
                float mh = mask[b*LL + h];
                if (mh == 0.f || mc == 0.f) continue;
                float eng = Sacc[at][bt][r] + SDb[h] + sev + bk;
                atomicAdd(&Ab[h*LL + c], __expf(eng));
                if (c >= 1 && tagc == k && headc == h) atomicAdd(&tgt[b], eng);
            }
        }
    }
}

// ---------------------------------------------------------------------------
// Sum the 8 A-slices into As
// ---------------------------------------------------------------------------
__global__ __launch_bounds__(256) void k_asum(
    const float4* __restrict__ A8, float4* __restrict__ As)
{
    const int f4 = blockIdx.x * 256 + threadIdx.x;   // < 32*4096
    const int b = f4 >> 12, r = f4 & 4095;
    float4 s = make_float4(0.f, 0.f, 0.f, 0.f);
#pragma unroll
    for (int g = 0; g < 8; ++g) {
        float4 v = A8[((size_t)(g*BB + b))*4096 + r];
        s.x += v.x; s.y += v.y; s.z += v.z; s.w += v.w;
    }
    As[f4] = s;
}

// ---------------------------------------------------------------------------
// Register-resident LU logdet (one block/batch, 16x16 thread grid, 8x8 regs).
// ---------------------------------------------------------------------------
__global__ __launch_bounds__(256) void k_logdet(
    const float* __restrict__ Asg, const int* __restrict__ lengths,
    const float* __restrict__ tgt, float* __restrict__ out)
{
    const int b = blockIdx.x;
    const int t = threadIdx.x;
    const int rg = t >> 4;      // 0..15 row-group
    const int cg = t & 15;      // 0..15 col-group

    __shared__ float As[LL*LL];     // 64 KB
    __shared__ float Dg[128];       // col sums, then pivot stash
    __shared__ float Lbuf[128];
    __shared__ float Ubuf[128];
    __shared__ float red[256];

    const float4* As4 = (const float4*)Asg;
    for (int f4 = t; f4 < 4096; f4 += 256)
        ((float4*)As)[f4] = As4[(size_t)b*4096 + f4];
    __syncthreads();

    if (t < 128) {
        float s = 0.f;
        for (int hr = 0; hr < LL; ++hr) s += As[hr*LL + t];
        Dg[t] = s * (1.0f + 1e-4f) + 1e-6f;
    }
    __syncthreads();

    const int n1 = lengths[b] - 1;
    float m[8][8];
#pragma unroll
    for (int r = 0; r < 8; ++r) {
        const int i = 8*rg + r;
#pragma unroll
        for (int c = 0; c < 8; ++c) {
            const int j = 8*cg + c;
            float v;
            if (i < n1 && j < n1)
                v = ((i == j) ? Dg[i+1] : 0.f) - As[(i+1)*LL + (j+1)];
            else
                v = (i == j) ? 1.f : 0.f;
            m[r][c] = v;
        }
    }
    __syncthreads();   // done reading Dg/As; Dg reused as pivot stash

    for (int j = 0; j < 127; ++j) {
        const int jg = j >> 3, jl = j & 7;
        if (cg == jg) {
#pragma unroll
            for (int c = 0; c < 8; ++c) {
                if (c == jl) {
#pragma unroll
                    for (int r = 0; r < 8; ++r) Lbuf[8*rg + r] = m[r][c];
                }
            }
        }
        if (rg == jg) {
#pragma unroll
            for (int r = 0; r < 8; ++r) {
                if (r == jl) {
#pragma unroll
                    for (int c = 0; c < 8; ++c) Ubuf[8*cg + c] = m[r][c];
                }
            }
        }
        __syncthreads();

        const float piv = Lbuf[j];
        if (t == j) Dg[j] = piv;
        const float rp = 1.0f / piv;
        float lr[8], ur[8];
#pragma unroll
        for (int r = 0; r < 8; ++r) lr[r] = Lbuf[8*rg + r] * rp;
#pragma unroll
        for (int c = 0; c < 8; ++c) ur[c] = Ubuf[8*cg + c];
#pragma unroll
        for (int r = 0; r < 8; ++r)
#pragma unroll
            for (int c = 0; c < 8; ++c)
                m[r][c] = fmaf(-lr[r], ur[c], m[r][c]);
        __syncthreads();
    }

    float lsum = 0.f;
    if (t < 127) lsum = logf(Dg[t]);
    red[t] = lsum;
    __syncthreads();
    for (int off = 128; off >= 1; off >>= 1) {
        if (t < off) red[t] += red[t + off];
        __syncthreads();
    }
    if (t == 0) out[b] = red[0] - tgt[b];
}

// ---------------------------------------------------------------------------
extern "C" void kernel_launch(void* const* d_in, const int* in_sizes, int n_in,
                              void* d_out, int out_size, void* d_ws, size_t ws_size,
                              hipStream_t stream) {
    const float* H    = (const float*)d_in[0];
    const float* C    = (const float*)d_in[1];
    const float* Wd   = (const float*)d_in[2];
    const float* We   = (const float*)d_in[3];
    const float* U    = (const float*)d_in[4];
    const float* bv   = (const float*)d_in[5];
    const float* mask = (const float*)d_in[6];
    const int* heads  = (const int*)d_in[7];
    const int* tags   = (const int*)d_in[8];
    const int* lens   = (const int*)d_in[9];
    float* out = (float*)d_out;

    // workspace layout
    char* p = (char*)d_ws;
    float* A8  = (float*)p;                 p += (size_t)8*BB*LL*LL*4;      // 16.78 MB
    float* tgt = (float*)p;                 p += 32*4;
    float* As  = (float*)p;                 p += (size_t)BB*LL*LL*4;        // 2.10 MB
    float* SDp = (float*)p;                 p += (size_t)BB*KK*LL*4;
    float* SEp = (float*)p;                 p += (size_t)BB*KK*LL*4;
    short* Hsp = (short*)p;                 p += (size_t)BB*SDN*LL*8*2;
    short* Csp = (short*)p;                 p += (size_t)BB*SEN*LL*8*2;
    short* Usp = (short*)p;                 p += (size_t)KK*SDN*EE*8*2;

    hipMemsetAsync(d_ws, 0, ((size_t)8*BB*LL*LL + 32)*4, stream);

    k_prep<<<dim3(6162), 256, 0, stream>>>(H, C, U, Wd, We, Hsp, Csp, Usp, SDp, SEp);
    k_mfma<<<dim3(KK*BB), 256, 0, stream>>>(Hsp, Csp, Usp, SDp, SEp, bv, mask,
                                            heads, tags, A8, tgt);
    k_asum<<<dim3(512), 256, 0, stream>>>((const float4*)A8, (float4*)As);
    k_logdet<<<dim3(BB), 256, 0, stream>>>(As, lens, tgt, out);
}

// Round 6
// 444.397 us; speedup vs baseline: 1.9533x; 1.0292x over previous
//
#include <hip/hip_runtime.h>
#include <hip/hip_bf16.h>

#define BB 32
#define LL 128
#define DD 400
#define KK 40
#define SDN 52   // d-slots padded (400/8 -> 52, zeros above 400)
#define SEN 52   // e-slots (416/8)
#define EP 512   // e padded for k_T M-tiles
#define KHALF 20

typedef __attribute__((ext_vector_type(8))) short bfrag;   // 8 bf16 (A/B frag 16x16x32)
typedef __attribute__((ext_vector_type(4))) float cfrag;   // 4 fp32 (C/D frag 16x16x32)

static __device__ __forceinline__ short f2bf(float f) {
    union { float f; unsigned u; } v; v.f = f;
    unsigned r = (v.u + 0x7FFF + ((v.u >> 16) & 1)) >> 16;
    return (short)r;
}
static __device__ __forceinline__ unsigned pack2(float a, float b) {
    return (unsigned)(unsigned short)f2bf(a) | ((unsigned)(unsigned short)f2bf(b) << 16);
}

// ---------------------------------------------------------------------------
// Hs[b][sd(52)][h][8] (d-pad zero), Cs[b][se(52)][c][8] (e-pad zero)
// ---------------------------------------------------------------------------
__global__ __launch_bounds__(256) void p_hc(
    const float* __restrict__ H, const float* __restrict__ C,
    short* __restrict__ Hs, short* __restrict__ Cs)
{
    int id = blockIdx.x * 256 + threadIdx.x;
    const int NH = BB*SDN*LL;
    if (id < NH) {
        int b = id / (SDN*LL); int r = id % (SDN*LL);
        int sd = r / LL; int h = r % LL;
        bfrag v;
#pragma unroll
        for (int j = 0; j < 8; ++j) {
            int d = sd*8 + j;
            v[j] = (d < DD) ? f2bf(H[((size_t)(b*LL + h))*DD + d]) : (short)0;
        }
        *(bfrag*)(Hs + (size_t)id*8) = v;
    } else if (id < 2*NH) {
        id -= NH;
        int b = id / (SEN*LL); int r = id % (SEN*LL);
        int se = r / LL; int c = r % LL;
        bfrag v;
#pragma unroll
        for (int j = 0; j < 8; ++j) {
            int e = se*8 + j;
            v[j] = (e < DD) ? f2bf(C[((size_t)(b*LL + c))*DD + e]) : (short)0;
        }
        *(bfrag*)(Cs + (size_t)id*8) = v;
    }
}

// Us[k][sd(52)][e(512)][8] = bf16(U[k][sd*8+j][e]); zero outside d<400, e<416
__global__ __launch_bounds__(256) void p_u(
    const float* __restrict__ U, short* __restrict__ Us)
{
    int id = blockIdx.x * 256 + threadIdx.x;   // < 40*52*512
    if (id >= KK*SDN*EP) return;
    int k = id / (SDN*EP); int r = id % (SDN*EP);
    int sd = r / EP; int e = r % EP;
    bfrag v;
#pragma unroll
    for (int j = 0; j < 8; ++j) {
        int d = sd*8 + j;
        v[j] = (d < DD && e < DD) ? f2bf(U[((size_t)k*DD + d)*DD + e]) : (short)0;
    }
    *(bfrag*)(Us + (size_t)id*8) = v;
}

// ---------------------------------------------------------------------------
// SD[b,k,h] = W_d[k].h[b,h]   SE[b,k,c] = W_e[k].c[b,c]   (fp32 exact)
// ---------------------------------------------------------------------------
__global__ __launch_bounds__(256) void k_sdse(
    const float* __restrict__ H, const float* __restrict__ C,
    const float* __restrict__ Wd, const float* __restrict__ We,
    float* __restrict__ SD, float* __restrict__ SE)
{
    const int k = blockIdx.x % KK;
    const int b = blockIdx.x / KK;
    const int t = threadIdx.x;
    __shared__ float wd[DD], we[DD];
    for (int f = t; f < DD; f += 256) { wd[f] = Wd[k*DD + f]; we[f] = We[k*DD + f]; }
    __syncthreads();
    const int row = t & 127;
    const float* src = (t < 128) ? (H + (size_t)(b*LL + row)*DD)
                                 : (C + (size_t)(b*LL + row)*DD);
    const float* w = (t < 128) ? wd : we;
    float s = 0.f;
    for (int d = 0; d < DD; d += 4) {
        float4 v = *(const float4*)(src + d);
        s = fmaf(v.x, w[d+0], s); s = fmaf(v.y, w[d+1], s);
        s = fmaf(v.z, w[d+2], s); s = fmaf(v.w, w[d+3], s);
    }
    if (t < 128) SD[(b*KK + k)*LL + row] = s;
    else         SE[(b*KK + k)*LL + row] = s;
}

// ---------------------------------------------------------------------------
// k_T: T[kk,b,e,h] = sum_d Ut[kk][e][d] * H[b][h][d]
// Block = (etile, b, k-in-half). 4 waves in 2x2; wave tile 64e x 64h as
// 4x4 16x16x32 frags (64 AGPR acc). Direct global frag loads, prefetch 1.
// Output: Tb[kh][b][se(52)][h(128)][8] bf16 (stores only e<416).
// ---------------------------------------------------------------------------
__global__ __launch_bounds__(256, 2) void k_T(
    const short* __restrict__ Us, const short* __restrict__ Hs,
    short* __restrict__ Tb, int k0)
{
    const int et = blockIdx.x;       // 0..3
    const int b  = blockIdx.y;       // 0..31
    const int kz = blockIdx.z;       // 0..KHALF-1
    const int kk = k0 + kz;
    const int t = threadIdx.x;
    const int w = t >> 6, l = t & 63;
    const int wr = w >> 1, wc = w & 1;
    const int l15 = l & 15, l4 = l >> 4;

    const int m0 = et*128 + wr*64;   // e base
    const int n0 = wc*64;            // h base

    const bfrag* A = (const bfrag*)(Us + (size_t)kk*SDN*EP*8);
    const bfrag* Bv = (const bfrag*)(Hs + (size_t)b*SDN*LL*8);

    cfrag acc[4][4];
#pragma unroll
    for (int i = 0; i < 4; ++i)
#pragma unroll
        for (int j = 0; j < 4; ++j)
#pragma unroll
            for (int r = 0; r < 4; ++r) acc[i][j][r] = 0.f;

    bfrag af[4], bf[4];
#pragma unroll
    for (int i = 0; i < 4; ++i) {
        af[i] = A[l4*EP + m0 + i*16 + l15];
        bf[i] = Bv[l4*LL + n0 + i*16 + l15];
    }
    for (int sdc = 0; sdc < 13; ++sdc) {
        bfrag afn[4], bfn[4];
        if (sdc < 12) {
            const int sdn = (sdc + 1)*4 + l4;
#pragma unroll
            for (int i = 0; i < 4; ++i) {
                afn[i] = A[sdn*EP + m0 + i*16 + l15];
                bfn[i] = Bv[sdn*LL + n0 + i*16 + l15];
            }
        } else {
#pragma unroll
            for (int i = 0; i < 4; ++i) { afn[i] = af[i]; bfn[i] = bf[i]; }
        }
#pragma unroll
        for (int mf = 0; mf < 4; ++mf)
#pragma unroll
            for (int nf = 0; nf < 4; ++nf)
                acc[mf][nf] = __builtin_amdgcn_mfma_f32_16x16x32_bf16(
                    af[mf], bf[nf], acc[mf][nf], 0, 0, 0);
#pragma unroll
        for (int i = 0; i < 4; ++i) { af[i] = afn[i]; bf[i] = bfn[i]; }
    }

    // store: row=m=e = m0+mf*16+l4*4+r, col=n=h = n0+nf*16+l15
    short* To = Tb + (size_t)(kz*BB + b)*SEN*LL*8;
#pragma unroll
    for (int mf = 0; mf < 4; ++mf) {
        const int e0 = m0 + mf*16 + l4*4;
        if (e0 < 416) {
            const int se = e0 >> 3, e7 = e0 & 7;
#pragma unroll
            for (int nf = 0; nf < 4; ++nf) {
                const int h = n0 + nf*16 + l15;
                uint2 pv;
                pv.x = pack2(acc[mf][nf][0], acc[mf][nf][1]);
                pv.y = pack2(acc[mf][nf][2], acc[mf][nf][3]);
                *(uint2*)(To + (size_t)(se*LL + h)*8 + e7) = pv;
            }
        }
    }
}

// ---------------------------------------------------------------------------
// k_S: S[h][c] = sum_e T[h][e] * c[c][e]; fused energy/exp/atomic epilogue.
// Block = (k-in-half, b). Same 4x4 16x16x32 wave tiling, A=Tb, B=Cs.
// ---------------------------------------------------------------------------
__global__ __launch_bounds__(256, 2) void k_S(
    const short* __restrict__ Tb, const short* __restrict__ Cs,
    const float* __restrict__ SD, const float* __restrict__ SE,
    const float* __restrict__ bvec, const float* __restrict__ mask,
    const int* __restrict__ heads, const int* __restrict__ tags,
    float* __restrict__ A8, float* __restrict__ tgt, int k0)
{
    const int kz = blockIdx.x;
    const int kk = k0 + kz;
    const int b  = blockIdx.y;
    const int t = threadIdx.x;
    const int w = t >> 6, l = t & 63;
    const int wr = w >> 1, wc = w & 1;
    const int l15 = l & 15, l4 = l >> 4;

    const int h0 = wr*64;
    const int c0 = wc*64;

    const bfrag* A = (const bfrag*)(Tb + (size_t)(kz*BB + b)*SEN*LL*8);
    const bfrag* Bv = (const bfrag*)(Cs + (size_t)b*SEN*LL*8);

    cfrag acc[4][4];
#pragma unroll
    for (int i = 0; i < 4; ++i)
#pragma unroll
        for (int j = 0; j < 4; ++j)
#pragma unroll
            for (int r = 0; r < 4; ++r) acc[i][j][r] = 0.f;

    bfrag af[4], bf[4];
#pragma unroll
    for (int i = 0; i < 4; ++i) {
        af[i] = A[l4*LL + h0 + i*16 + l15];
        bf[i] = Bv[l4*LL + c0 + i*16 + l15];
    }
    for (int esc = 0; esc < 13; ++esc) {
        bfrag afn[4], bfn[4];
        if (esc < 12) {
            const int sen = (esc + 1)*4 + l4;
#pragma unroll
            for (int i = 0; i < 4; ++i) {
                afn[i] = A[sen*LL + h0 + i*16 + l15];
                bfn[i] = Bv[sen*LL + c0 + i*16 + l15];
            }
        } else {
#pragma unroll
            for (int i = 0; i < 4; ++i) { afn[i] = af[i]; bfn[i] = bf[i]; }
        }
#pragma unroll
        for (int mf = 0; mf < 4; ++mf)
#pragma unroll
            for (int nf = 0; nf < 4; ++nf)
                acc[mf][nf] = __builtin_amdgcn_mfma_f32_16x16x32_bf16(
                    af[mf], bf[nf], acc[mf][nf], 0, 0, 0);
#pragma unroll
        for (int i = 0; i < 4; ++i) { af[i] = afn[i]; bf[i] = bfn[i]; }
    }

    // Epilogue: row=m=h = h0+mf*16+l4*4+r, col=n=c = c0+nf*16+l15
    const float bk = bvec[kk];
    const float* SDb = SD + ((size_t)b*KK + kk)*LL;
    const float* SEb = SE + ((size_t)b*KK + kk)*LL;
    float* Ab = A8 + (size_t)((kk & 7)*BB + b)*LL*LL;

#pragma unroll
    for (int nf = 0; nf < 4; ++nf) {
        const int c = c0 + nf*16 + l15;
        const float mc = mask[b*LL + c];
        const float sev = SEb[c];
        const int headc = heads[b*LL + c];
        const int tagc  = tags[b*LL + c];
#pragma unroll
        for (int mf = 0; mf < 4; ++mf) {
            const int hb = h0 + mf*16 + l4*4;
#pragma unroll
            for (int r = 0; r < 4; ++r) {
                const int h = hb + r;
                if (h == c) continue;
                const float mh = mask[b*LL + h];
                if (mh == 0.f || mc == 0.f) continue;
                float eng = acc[mf][nf][r] + SDb[h] + sev + bk;
                atomicAdd(&Ab[h*LL + c], __expf(eng));
                if (c >= 1 && tagc == kk && headc == h) atomicAdd(&tgt[b], eng);
            }
        }
    }
}

// ---------------------------------------------------------------------------
// Sum the 8 A-slices into As
// ---------------------------------------------------------------------------
__global__ __launch_bounds__(256) void k_asum(
    const float4* __restrict__ A8, float4* __restrict__ As)
{
    const int f4 = blockIdx.x * 256 + threadIdx.x;   // < 32*4096
    const int b = f4 >> 12, r = f4 & 4095;
    float4 s = make_float4(0.f, 0.f, 0.f, 0.f);
#pragma unroll
    for (int g = 0; g < 8; ++g) {
        float4 v = A8[((size_t)(g*BB + b))*4096 + r];
        s.x += v.x; s.y += v.y; s.z += v.z; s.w += v.w;
    }
    As[f4] = s;
}

// ---------------------------------------------------------------------------
// Register-resident LU logdet (one block/batch, 16x16 thread grid, 8x8 regs).
// ---------------------------------------------------------------------------
__global__ __launch_bounds__(256) void k_logdet(
    const float* __restrict__ Asg, const int* __restrict__ lengths,
    const float* __restrict__ tgt, float* __restrict__ out)
{
    const int b = blockIdx.x;
    const int t = threadIdx.x;
    const int rg = t >> 4;
    const int cg = t & 15;

    __shared__ float As[LL*LL];
    __shared__ float Dg[128];
    __shared__ float Lbuf[128];
    __shared__ float Ubuf[128];
    __shared__ float red[256];

    const float4* As4 = (const float4*)Asg;
    for (int f4 = t; f4 < 4096; f4 += 256)
        ((float4*)As)[f4] = As4[(size_t)b*4096 + f4];
    __syncthreads();

    if (t < 128) {
        float s = 0.f;
        for (int hr = 0; hr < LL; ++hr) s += As[hr*LL + t];
        Dg[t] = s * (1.0f + 1e-4f) + 1e-6f;
    }
    __syncthreads();

    const int n1 = lengths[b] - 1;
    float m[8][8];
#pragma unroll
    for (int r = 0; r < 8; ++r) {
        const int i = 8*rg + r;
#pragma unroll
        for (int c = 0; c < 8; ++c) {
            const int j = 8*cg + c;
            float v;
            if (i < n1 && j < n1)
                v = ((i == j) ? Dg[i+1] : 0.f) - As[(i+1)*LL + (j+1)];
            else
                v = (i == j) ? 1.f : 0.f;
            m[r][c] = v;
        }
    }
    __syncthreads();

    for (int j = 0; j < 127; ++j) {
        const int jg = j >> 3, jl = j & 7;
        if (cg == jg) {
#pragma unroll
            for (int c = 0; c < 8; ++c) {
                if (c == jl) {
#pragma unroll
                    for (int r = 0; r < 8; ++r) Lbuf[8*rg + r] = m[r][c];
                }
            }
        }
        if (rg == jg) {
#pragma unroll
            for (int r = 0; r < 8; ++r) {
                if (r == jl) {
#pragma unroll
                    for (int c = 0; c < 8; ++c) Ubuf[8*cg + c] = m[r][c];
                }
            }
        }
        __syncthreads();

        const float piv = Lbuf[j];
        if (t == j) Dg[j] = piv;
        const float rp = 1.0f / piv;
        float lr[8], ur[8];
#pragma unroll
        for (int r = 0; r < 8; ++r) lr[r] = Lbuf[8*rg + r] * rp;
#pragma unroll
        for (int c = 0; c < 8; ++c) ur[c] = Ubuf[8*cg + c];
#pragma unroll
        for (int r = 0; r < 8; ++r)
#pragma unroll
            for (int c = 0; c < 8; ++c)
                m[r][c] = fmaf(-lr[r], ur[c], m[r][c]);
        __syncthreads();
    }

    float lsum = 0.f;
    if (t < 127) lsum = logf(Dg[t]);
    red[t] = lsum;
    __syncthreads();
    for (int off = 128; off >= 1; off >>= 1) {
        if (t < off) red[t] += red[t + off];
        __syncthreads();
    }
    if (t == 0) out[b] = red[0] - tgt[b];
}

// ---------------------------------------------------------------------------
extern "C" void kernel_launch(void* const* d_in, const int* in_sizes, int n_in,
                              void* d_out, int out_size, void* d_ws, size_t ws_size,
                              hipStream_t stream) {
    const float* H    = (const float*)d_in[0];
    const float* C    = (const float*)d_in[1];
    const float* Wd   = (const float*)d_in[2];
    const float* We   = (const float*)d_in[3];
    const float* U    = (const float*)d_in[4];
    const float* bv   = (const float*)d_in[5];
    const float* mask = (const float*)d_in[6];
    const int* heads  = (const int*)d_in[7];
    const int* tags   = (const int*)d_in[8];
    const int* lens   = (const int*)d_in[9];
    float* out = (float*)d_out;

    // workspace layout (~112 MB)
    char* p = (char*)d_ws;
    float* A8  = (float*)p;                 p += (size_t)8*BB*LL*LL*4;      // 16.78 MB
    float* tgt = (float*)p;                 p += 128*4;
    float* As  = (float*)p;                 p += (size_t)BB*LL*LL*4;        // 2.10 MB
    float* SDp = (float*)p;                 p += (size_t)BB*KK*LL*4;        // 0.66 MB
    float* SEp = (float*)p;                 p += (size_t)BB*KK*LL*4;        // 0.66 MB
    short* Hsp = (short*)p;                 p += (size_t)BB*SDN*LL*8*2;     // 3.41 MB
    short* Csp = (short*)p;                 p += (size_t)BB*SEN*LL*8*2;     // 3.41 MB
    short* Usp = (short*)p;                 p += (size_t)KK*SDN*EP*8*2;     // 17.04 MB
    short* Tbp = (short*)p;                 p += (size_t)KHALF*BB*SEN*LL*8*2; // 68.16 MB

    hipMemsetAsync(d_ws, 0, ((size_t)8*BB*LL*LL + 128)*4, stream);

    p_hc  <<<dim3(1664), 256, 0, stream>>>(H, C, Hsp, Csp);
    p_u   <<<dim3(4160), 256, 0, stream>>>(U, Usp);
    k_sdse<<<dim3(BB*KK), 256, 0, stream>>>(H, C, Wd, We, SDp, SEp);

    for (int half = 0; half < 2; ++half) {
        const int k0 = half * KHALF;
        k_T<<<dim3(4, BB, KHALF), 256, 0, stream>>>(Usp, Hsp, Tbp, k0);
        k_S<<<dim3(KHALF, BB), 256, 0, stream>>>(Tbp, Csp, SDp, SEp, bv, mask,
                                                 heads, tags, A8, tgt, k0);
    }

    k_asum<<<dim3(512), 256, 0, stream>>>((const float4*)A8, (float4*)As);
    k_logdet<<<dim3(BB), 256, 0, stream>>>(As, lens, tgt, out);
}